// Round 2
// baseline (544.311 us; speedup 1.0000x reference)
//
#include <hip/hip_runtime.h>
#include <hip/hip_bf16.h>

typedef unsigned short ushort_t;

#define BSZ 32
#define TT 50
#define TS 49

// ---- ws layout (float offsets) ----
#define OFF_VQ    0u        // 100
#define OFF_VK    128u      // 100
#define OFF_SC    256u      // [cq, ck, bw, w1, w2]
#define OFF_BIHH  288u      // 400 (b_ih + b_hh)
#define OFF_GPRE  704u      // 32*49*400 = 627200
#define OFF_IDX   627904u   // 32*49*10 (int)
#define OFF_NV    643584u   // 32*49 (int)
// total ~645152 floats ~2.58 MB

__device__ __forceinline__ ushort_t f2b(float f) {
    unsigned u = __float_as_uint(f);
    unsigned r = u + 0x7fffu + ((u >> 16) & 1u);
    return (ushort_t)(r >> 16);
}
__device__ __forceinline__ float sigm(float x) { return 1.f / (1.f + expf(-x)); }

__device__ __forceinline__ float dot100(const float* __restrict__ w, const float* __restrict__ x) {
    float acc = 0.f;
    for (int k = 0; k < 100; k += 4) {
        float4 a = *(const float4*)(w + k);
        float4 b = *(const float4*)(x + k);
        acc += a.x*b.x + a.y*b.y + a.z*b.z + a.w*b.w;
    }
    return acc;
}

// ---------------- prep kernel ----------------
__global__ __launch_bounds__(256) void kprep(
    const float* __restrict__ wq, const float* __restrict__ bq,
    const float* __restrict__ wk, const float* __restrict__ bk,
    const float* __restrict__ ww, const float* __restrict__ bw,
    const float* __restrict__ w1, const float* __restrict__ w2,
    const float* __restrict__ bih, const float* __restrict__ bhh,
    float* __restrict__ WS)
{
    int tid = threadIdx.x;
    for (int i = tid; i < 400; i += 256) WS[OFF_BIHH + i] = bih[i] + bhh[i];
    if (tid < 100) {
        float a1 = 0.f, a2 = 0.f;
        for (int d = 0; d < 100; ++d) {
            a1 += ww[d]       * wq[d*100 + tid];
            a2 += ww[100 + d] * wk[d*100 + tid];
        }
        WS[OFF_VQ + tid] = a1;
        WS[OFF_VK + tid] = a2;
    }
    if (tid == 0) {
        float cq = 0.f, ck = 0.f;
        for (int d = 0; d < 100; ++d) {
            cq += bq[d] * ww[d];
            ck += bk[d] * ww[100 + d];
        }
        WS[OFF_SC + 0] = cq;
        WS[OFF_SC + 1] = ck;
        WS[OFF_SC + 2] = bw[0];
        WS[OFF_SC + 3] = w1[0];
        WS[OFF_SC + 4] = w2[0];
    }
}

// ---------------- aggregation ----------------
struct AggBufs {
    float *b2in, *s2, *x1, *v1a, *v1b, *x0, *v0a, *v0b;
    int *n1, *n2, *n3;
};

__device__ void aggregate(int root, const int* __restrict__ tabA, const int* __restrict__ tabB,
                          const float* __restrict__ embE, const float* __restrict__ embO,
                          const float* __restrict__ aggw, const float* __restrict__ aggb,
                          const float* __restrict__ wlast, const float* __restrict__ blast,
                          AggBufs sb, float* outE, int tid)
{
    if (tid < 6) sb.n1[tid] = tabA[root*6 + tid];
    __syncthreads();
    if (tid < 36) sb.n2[tid] = tabB[sb.n1[tid/6]*6 + (tid % 6)];
    __syncthreads();
    for (int i = tid; i < 216; i += 256) sb.n3[i] = tabA[sb.n2[i/6]*6 + (i % 6)];
    __syncthreads();
    // inputs for i=0: raw embedding + mean of children
    for (int e = tid; e < 3600; e += 256) {
        int v = e / 100, d = e - v*100;
        float acc = embE[(size_t)sb.n2[v]*100 + d];
        float s3 = 0.f;
        const int* n3 = sb.n3 + v*6;
        for (int c = 0; c < 6; ++c) s3 += embO[(size_t)n3[c]*100 + d];
        sb.b2in[v*100 + d] = acc + s3 * (1.f/6.f);
    }
    for (int e = tid; e < 600; e += 256) {
        int a = e / 100, d = e - a*100;
        float acc = embO[(size_t)sb.n1[a]*100 + d];
        float s = 0.f;
        for (int bb = 0; bb < 6; ++bb) s += embE[(size_t)sb.n2[a*6 + bb]*100 + d];
        sb.x1[a*100 + d] = acc + s * (1.f/6.f);
    }
    for (int dd = tid; dd < 100; dd += 256) {
        float acc = embE[(size_t)root*100 + dd];
        float s = 0.f;
        for (int a = 0; a < 6; ++a) s += embO[(size_t)sb.n1[a]*100 + dd];
        sb.x0[dd] = acc + s * (1.f/6.f);
    }
    __syncthreads();
    // i=0: j=2 (s2[a] = sum of 6 tanh'd children, no atomics), j=1, j=0
    for (int o = tid; o < 600; o += 256) {
        int a = o % 6, d = o / 6;
        float s = 0.f;
        for (int c = 0; c < 6; ++c)
            s += tanhf(aggb[200 + d] + dot100(aggw + 20000 + d*100, sb.b2in + (a*6 + c)*100));
        sb.s2[a*100 + d] = s;
    }
    for (int o = tid; o < 600; o += 256) {
        int v = o % 6, d = o / 6;
        sb.v1a[v*100 + d] = tanhf(aggb[100 + d] + dot100(aggw + 10000 + d*100, sb.x1 + v*100));
    }
    for (int dd = tid; dd < 100; dd += 256)
        sb.v0a[dd] = tanhf(aggb[dd] + dot100(aggw + dd*100, sb.x0));
    __syncthreads();
    // i=1 inputs
    for (int e = tid; e < 600; e += 256) sb.x1[e] = sb.v1a[e] + sb.s2[e] * (1.f/6.f);
    for (int dd = tid; dd < 100; dd += 256) {
        float s = 0.f;
        for (int a = 0; a < 6; ++a) s += sb.v1a[a*100 + dd];
        sb.x0[dd] = sb.v0a[dd] + s * (1.f/6.f);
    }
    __syncthreads();
    // i=1: j=1, j=0
    for (int o = tid; o < 600; o += 256) {
        int v = o % 6, d = o / 6;
        sb.v1b[v*100 + d] = tanhf(aggb[100 + d] + dot100(aggw + 10000 + d*100, sb.x1 + v*100));
    }
    for (int dd = tid; dd < 100; dd += 256)
        sb.v0b[dd] = tanhf(aggb[dd] + dot100(aggw + dd*100, sb.x0));
    __syncthreads();
    // i=2 input
    for (int dd = tid; dd < 100; dd += 256) {
        float s = 0.f;
        for (int a = 0; a < 6; ++a) s += sb.v1b[a*100 + dd];
        sb.x0[dd] = sb.v0b[dd] + s * (1.f/6.f);
    }
    __syncthreads();
    for (int dd = tid; dd < 100; dd += 256)
        sb.v0a[dd] = tanhf(aggb[dd] + dot100(aggw + dd*100, sb.x0));
    __syncthreads();
    // final projection
    for (int dd = tid; dd < 100; dd += 256)
        outE[dd] = tanhf(blast[dd] + dot100(wlast + dd*100, sb.v0a));
}

// ---------------- per-(b,t) parallel kernel ----------------
__global__ __launch_bounds__(256) void kmain(
    const int* __restrict__ user, const int* __restrict__ question, const int* __restrict__ response,
    const int* __restrict__ mask, const int* __restrict__ qnbr, const int* __restrict__ snbr,
    const int* __restrict__ unbr, const int* __restrict__ qnbr2,
    const float* __restrict__ embQ, const float* __restrict__ embQ2, const float* __restrict__ embS,
    const float* __restrict__ embU, const float* __restrict__ embR,
    const float* __restrict__ aggw, const float* __restrict__ aggb,
    const float* __restrict__ wlast, const float* __restrict__ blast,
    const float* __restrict__ wfus, const float* __restrict__ bfus,
    const float* __restrict__ wih,
    float* __restrict__ WS)
{
    int bid = blockIdx.x;
    int b = bid / TS, t = bid - b*TS;
    int tid = threadIdx.x;

    __shared__ __align__(16) float sB2in[3600];
    __shared__ __align__(16) float sS2[600];
    __shared__ __align__(16) float sX1[600];
    __shared__ __align__(16) float sV1a[600], sV1b[600];
    __shared__ __align__(16) float sX0[100], sV0a[100], sV0b[100];
    __shared__ __align__(16) float sE1[100], sE2[100];
    __shared__ __align__(16) float sEIN[200], sET[100], sEQN[100];
    __shared__ float sScore[52];
    __shared__ int sN1[8], sN2[36], sN3[216];

    int q_t = question[b*TT + t];
    int u_t = user[b*TT + t];
    int r_t = response[b*TT + t];
    int mm  = mask[b*TT + t];

    AggBufs sb { sB2in, sS2, sX1, sV1a, sV1b, sX0, sV0a, sV0b, sN1, sN2, sN3 };
    if (mm == 1) {
        aggregate(q_t, qnbr, snbr, embQ, embS, aggw, aggb, wlast, blast, sb, sE1, tid);
        __syncthreads();
        aggregate(u_t, unbr, qnbr2, embU, embQ2, aggw, aggb, wlast, blast, sb, sE2, tid);
    } else {
        for (int dd = tid; dd < 100; dd += 256) {
            sE1[dd] = embQ[(size_t)q_t*100 + dd];
            sE2[dd] = embQ2[(size_t)q_t*100 + dd];
        }
    }
    __syncthreads();
    float w1 = WS[OFF_SC + 3], w2 = WS[OFF_SC + 4];
    for (int dd = tid; dd < 100; dd += 256) {
        sEIN[dd]       = w1*sE1[dd] + w2*sE2[dd];
        sEIN[100 + dd] = embR[r_t*100 + dd];
    }
    __syncthreads();
    // fusion: e_t = relu(W_fusion (100x200) @ ein + b_fusion)
    for (int o = tid; o < 100; o += 256) {
        float acc = bfus[o];
        const float* wr = wfus + o*200;
        for (int k = 0; k < 200; k += 4) {
            float4 a = *(const float4*)(wr + k);
            float4 x = *(const float4*)(sEIN + k);
            acc += a.x*x.x + a.y*x.y + a.z*x.z + a.w*x.w;
        }
        sET[o] = fmaxf(acc, 0.f);
    }
    __syncthreads();
    size_t bt = (size_t)b*TS + t;
    // Gpre = e_t @ W_ih^T + (b_ih + b_hh)
    for (int o = tid; o < 400; o += 256)
        WS[OFF_GPRE + bt*400 + o] = WS[OFF_BIHH + o] + dot100(wih + o*100, sET);

    // ---- rank-K score + top-k for step t (uses question[t+1]) ----
    int qn = question[b*TT + t + 1];
    for (int dd = tid; dd < 100; dd += 256) sEQN[dd] = embQ[(size_t)qn*100 + dd];
    __syncthreads();
    for (int tp = tid; tp < 50; tp += 256) {
        if (tp < t) {
            int qq = question[b*TT + tp];
            float acc = 0.f;
            for (int k = 0; k < 100; ++k) acc += embQ[(size_t)qq*100 + k] * sEQN[k];
            sScore[tp] = acc;
        }
    }
    __syncthreads();
    if (tid == 64) {
        int nv = t < 10 ? t : 10;
        ((int*)(WS + OFF_NV))[bt] = nv;
        int* idxp = (int*)(WS + OFF_IDX) + bt*10;
        unsigned long long taken = 0ull;
        for (int p = 0; p < nv; ++p) {
            float best = -3.0e38f; int bi = 0;
            for (int tp2 = 0; tp2 < t; ++tp2) {
                if (!((taken >> tp2) & 1ull) && sScore[tp2] > best) { best = sScore[tp2]; bi = tp2; }
            }
            taken |= (1ull << bi);
            idxp[p] = bi;
        }
    }
}

// ---------------- sequential scan kernel (one block per batch element) ----------------
__global__ __launch_bounds__(512) void kseq(
    const int* __restrict__ question, const int* __restrict__ qsidx, const int* __restrict__ mask,
    const float* __restrict__ whh, const float* __restrict__ embQ, const float* __restrict__ embS,
    const float* __restrict__ WS, float* __restrict__ out)
{
    int b = blockIdx.x, tid = threadIdx.x;
    __shared__ ushort_t sWHH[400*102];   // bf16-rounded W_hh, pitch 102
    __shared__ float sSH[TT*100];
    __shared__ float sH[100], sC[100], sG[400], sQSC[500], sVQl[100], sVKl[100];
    __shared__ float sKL[12], sGv[60], sQL5[8];
    __shared__ int sIdx[12];
    __shared__ int sNv;

    for (int i = tid; i < 40000; i += 512) {
        int g = i / 100, k = i - g*100;
        sWHH[g*102 + k] = f2b(whh[i]);
    }
    for (int i = tid; i < 100; i += 512) {
        sH[i] = 0.f; sC[i] = 0.f;
        sVQl[i] = WS[OFF_VQ + i];
        sVKl[i] = WS[OFF_VK + i];
    }
    float cq = WS[OFF_SC + 0], ck = WS[OFF_SC + 1], bw = WS[OFF_SC + 2];
    if (tid == 0) out[b*TT] = 0.5f;
    __syncthreads();

    for (int t = 0; t < TS; ++t) {
        size_t bt = (size_t)b*TS + t;
        // gates = Gpre + h @ W_hh^T  (W_hh in bf16)
        for (int g = tid; g < 400; g += 512) {
            float acc = WS[OFF_GPRE + bt*400 + g];
            const ushort_t* wr = sWHH + g*102;
            for (int k = 0; k < 100; k += 2) {
                unsigned u = *(const unsigned*)(wr + k);
                acc += __uint_as_float(u << 16) * sH[k] + __uint_as_float(u & 0xffff0000u) * sH[k+1];
            }
            sG[g] = acc;
        }
        __syncthreads();
        int mm = mask[b*TT + t];
        for (int dd = tid; dd < 100; dd += 512) {
            float gi = sG[dd], gf = sG[100+dd], gg = sG[200+dd], go = sG[300+dd];
            float c2 = sigm(gf)*sC[dd] + sigm(gi)*tanhf(gg);
            float h2 = sigm(go)*tanhf(c2);
            if (mm == 1) { sH[dd] = h2; sC[dd] = c2; }
            sSH[t*100 + dd] = sH[dd];
        }
        // gather qs_concat for this step
        int qn = question[b*TT + t + 1];
        for (int i = tid; i < 500; i += 512) {
            int q = i / 100, dd = i - q*100;
            sQSC[i] = (q == 0) ? embQ[(size_t)qn*100 + dd]
                               : embS[(size_t)qsidx[qn*4 + (q-1)]*100 + dd];
        }
        if (tid < 10) sIdx[tid] = ((const int*)(WS + OFF_IDX))[bt*10 + tid];
        if (tid == 0) sNv = ((const int*)(WS + OFF_NV))[bt];
        __syncthreads();
        int nv = sNv, nst = nv + 1;
        // kl for each state
        if (tid < nst) {
            const float* st = (tid == 0) ? sH : (sSH + sIdx[tid-1]*100);
            float acc = ck;
            for (int k = 0; k < 100; ++k) acc += st[k] * sVKl[k];
            sKL[tid] = acc;
        }
        // ql for the 5 query rows
        if (tid >= 64 && tid < 69) {
            int q = tid - 64;
            float acc = cq;
            for (int k = 0; k < 100; ++k) acc += sQSC[q*100 + k] * sVQl[k];
            sQL5[q] = acc;
        }
        // g matrix
        for (int j = tid; j < 5*nst; j += 512) {
            int q = j / nst, s = j - q*nst;
            const float* st = (s == 0) ? sH : (sSH + sIdx[s-1]*100);
            const float* xq = sQSC + q*100;
            float acc = 0.f;
            for (int k = 0; k < 100; ++k) acc += xq[k] * st[k];
            sGv[q*11 + s] = acc;
        }
        __syncthreads();
        if (tid < 64) {
            int tot = 5*nst;
            bool valid = tid < tot;
            int q = 0, s = 0;
            if (valid) { q = tid / nst; s = tid - q*nst; }
            float lg = valid ? (sQL5[q] + sKL[s] + bw) : -3.0e38f;
            float mx = lg;
            for (int m2 = 1; m2 < 64; m2 <<= 1) mx = fmaxf(mx, __shfl_xor(mx, m2, 64));
            float e  = valid ? expf(lg - mx) : 0.f;
            float gv = valid ? sGv[q*11 + s] : 0.f;
            float se = e, sg = e*gv;
            for (int m2 = 1; m2 < 64; m2 <<= 1) {
                se += __shfl_xor(se, m2, 64);
                sg += __shfl_xor(sg, m2, 64);
            }
            if (tid == 0) out[b*TT + t + 1] = 1.f / (1.f + expf(-(sg/se)));
        }
        __syncthreads();
    }
}

extern "C" void kernel_launch(void* const* d_in, const int* in_sizes, int n_in,
                              void* d_out, int out_size, void* d_ws, size_t ws_size,
                              hipStream_t stream) {
    const int* user      = (const int*)d_in[0];
    const int* question  = (const int*)d_in[1];
    const int* response  = (const int*)d_in[2];
    const int* mask      = (const int*)d_in[3];
    const int* qnbr      = (const int*)d_in[4];
    const int* snbr      = (const int*)d_in[5];
    const int* unbr      = (const int*)d_in[6];
    const int* qnbr2     = (const int*)d_in[7];
    const int* qsidx     = (const int*)d_in[8];
    const float* embQ    = (const float*)d_in[9];
    const float* embQ2   = (const float*)d_in[10];
    const float* embS    = (const float*)d_in[11];
    const float* embU    = (const float*)d_in[12];
    const float* embR    = (const float*)d_in[13];
    const float* w1      = (const float*)d_in[14];
    const float* w2      = (const float*)d_in[15];
    const float* wih     = (const float*)d_in[16];
    const float* whh     = (const float*)d_in[17];
    const float* bih     = (const float*)d_in[18];
    const float* bhh     = (const float*)d_in[19];
    const float* aggw    = (const float*)d_in[20];
    const float* aggb    = (const float*)d_in[21];
    const float* wlast   = (const float*)d_in[22];
    const float* blast   = (const float*)d_in[23];
    const float* wq      = (const float*)d_in[24];
    const float* bq      = (const float*)d_in[25];
    const float* wk      = (const float*)d_in[26];
    const float* bk      = (const float*)d_in[27];
    const float* ww      = (const float*)d_in[28];
    const float* bwp     = (const float*)d_in[29];
    const float* wfus    = (const float*)d_in[30];
    const float* bfus    = (const float*)d_in[31];
    float* WS = (float*)d_ws;
    float* out = (float*)d_out;

    hipLaunchKernelGGL(kprep, dim3(1), dim3(256), 0, stream,
                       wq, bq, wk, bk, ww, bwp, w1, w2, bih, bhh, WS);
    hipLaunchKernelGGL(kmain, dim3(BSZ*TS), dim3(256), 0, stream,
                       user, question, response, mask, qnbr, snbr, unbr, qnbr2,
                       embQ, embQ2, embS, embU, embR,
                       aggw, aggb, wlast, blast, wfus, bfus, wih, WS);
    hipLaunchKernelGGL(kseq, dim3(BSZ), dim3(512), 0, stream,
                       question, qsidx, mask, whh, embQ, embS, WS, out);
}